// Round 13
// baseline (797.839 us; speedup 1.0000x reference)
//
#include <hip/hip_runtime.h>

#define HIDN 4096
#define KEXT 4224
#define TTOK 4096
#define SEQL 1024
#define NB 4
#define NHEAD 32
#define SCALEF 0.08838834764831845f

typedef __attribute__((ext_vector_type(8))) short bf16x8;
typedef __attribute__((ext_vector_type(8))) unsigned short u16x8;
typedef __attribute__((ext_vector_type(4))) float f32x4;

static __device__ __forceinline__ unsigned short f2bf(float f) {
  union { float f; unsigned u; } v; v.f = f;
  unsigned r = v.u + 0x7fffu + ((v.u >> 16) & 1u);
  return (unsigned short)(r >> 16);
}
static __device__ __forceinline__ void load_lds16(const void* g, void* l) {
  __builtin_amdgcn_global_load_lds((const __attribute__((address_space(1))) void*)g,
                                   (__attribute__((address_space(3))) void*)l, 16, 0, 0);
}

// ---------------- fp32 -> bf16 cast (contiguous): grid = n/1024 blocks ----------------
__global__ __launch_bounds__(256) void f2b_kernel(const float* __restrict__ s,
                                                  unsigned short* __restrict__ d) {
  size_t i = ((size_t)blockIdx.x * 256 + threadIdx.x) * 4;
  float4 v = *(const float4*)(s + i);
  ushort4 o;
  o.x = f2bf(v.x); o.y = f2bf(v.y); o.z = f2bf(v.z); o.w = f2bf(v.w);
  *(ushort4*)(d + i) = o;
}

// ---------------- fp32 [R][4096] -> bf16 dst[R][KEXT] cols 0..4095 ----------------
__global__ __launch_bounds__(256) void f2b_pad_kernel(const float* __restrict__ s,
                                                      unsigned short* __restrict__ d) {
  size_t i = ((size_t)blockIdx.x * 256 + threadIdx.x) * 4;
  int row = (int)(i >> 12);
  int col = (int)(i & 4095);
  float4 v = *(const float4*)(s + i);
  ushort4 o;
  o.x = f2bf(v.x); o.y = f2bf(v.y); o.z = f2bf(v.z); o.w = f2bf(v.w);
  *(ushort4*)(d + (size_t)row * KEXT + col) = o;
}

// ---------------- merged: W pad-cast + wb fold into Wext ----------------
__global__ __launch_bounds__(256) void conv_w_kernel(const float* __restrict__ W,
    const float* __restrict__ wb, unsigned short* __restrict__ wext) {
  int bid = blockIdx.x;
  if (bid < 16384) {
    size_t i = ((size_t)bid * 256 + threadIdx.x) * 4;
    int row = (int)(i >> 12);
    int col = (int)(i & 4095);
    float4 v = *(const float4*)(W + i);
    ushort4 o;
    o.x = f2bf(v.x); o.y = f2bf(v.y); o.z = f2bf(v.z); o.w = f2bf(v.w);
    *(ushort4*)(wext + (size_t)row * KEXT + col) = o;
  } else {
    int idx = (bid - 16384) * 256 + threadIdx.x;
    int o = idx >> 5;
    int j4 = (idx & 31) * 4;
    int l = j4 >> 4, r = j4 & 15;
    float4 v = *(const float4*)(wb + ((size_t)l * HIDN + o) * 16 + r);
    ushort4 q;
    q.x = f2bf(v.x); q.y = f2bf(v.y); q.z = f2bf(v.z); q.w = f2bf(v.w);
    *(ushort4*)(wext + (size_t)o * KEXT + 4096 + j4) = q;
  }
}

// ---------------- merged: three wa tensors -> WAbf in one launch ----------------
__global__ __launch_bounds__(256) void conv_wa3_kernel(const float* __restrict__ s0,
    const float* __restrict__ s1, const float* __restrict__ s2,
    unsigned short* __restrict__ d) {
  int sel = blockIdx.x >> 9;
  const float* s = (sel == 0) ? s0 : ((sel == 1) ? s1 : s2);
  size_t i = ((size_t)(blockIdx.x & 511) * 256 + threadIdx.x) * 4;
  float4 v = *(const float4*)(s + i);
  ushort4 o;
  o.x = f2bf(v.x); o.y = f2bf(v.y); o.z = f2bf(v.z); o.w = f2bf(v.w);
  *(ushort4*)(d + (size_t)sel * 128 * HIDN + i) = o;
}

// ---------------- Afat: one-hot-expanded lora activations -> Xext cols 4096..4223 ----------------
__global__ __launch_bounds__(128) void afat_kernel(const float* __restrict__ afull, int aoff,
    int awidth, const int* __restrict__ lidx, unsigned short* __restrict__ xext) {
  int t = blockIdx.x, j = threadIdx.x;
  int l = lidx[t];
  float v = afull[(size_t)t * awidth + aoff + j];
  unsigned short o = ((j >> 4) == l) ? f2bf(v) : (unsigned short)0;
  xext[(size_t)t * KEXT + 4096 + j] = o;
}

// ---------------- rope tables ----------------
__global__ __launch_bounds__(256) void rope_tab_kernel(float* __restrict__ cosb,
                                                       float* __restrict__ sinb) {
  int i = blockIdx.x * 256 + threadIdx.x;
  int s = i >> 6, j = i & 63;
  float inv = __expf(-__logf(10000.0f) * (float)j * (1.0f / 64.0f));
  float f = (float)s * inv;
  cosb[i] = cosf(f);
  sinb[i] = sinf(f);
}

// =================== 256x256 GEMM: m201-style fine-phase convoy ===================
// Per phase: {issue ds_reads + 2 glds} -> s_barrier -> lgkmcnt(0) -> 16 MFMA -> s_barrier.
// 4 phases per 64-K tile; counted vmcnt(4) before the P1-end and P3-end barriers
// (issue->wait distance = 4 phases, unchanged data-flow from the verified R5 schedule).
// B frags read once per k-half (P0/P2), reused in P1/P3.
#define GPHASE_BAR_WAIT()                                     \
  __builtin_amdgcn_sched_barrier(0);                          \
  __builtin_amdgcn_s_barrier();                               \
  asm volatile("s_waitcnt lgkmcnt(0)" ::: "memory");          \
  __builtin_amdgcn_sched_barrier(0);

template<int BUF, bool ST>
__device__ __forceinline__ void ktile(char* lds, f32x4 (&acc)[8][4], int a_rd, int b_rd,
    const unsigned short* aS0, const unsigned short* aS1,
    const unsigned short* bS0, const unsigned short* bS1, int stg, int kn) {
  const int NB_ = (BUF ^ 1) * 32768;
  bf16x8 af[4], bfr[4];
  // ---- P0: k0, rows 0-63; read A+B; issue A-k0(t+1) ----
  #pragma unroll
  for (int mi = 0; mi < 4; ++mi)
    af[mi] = *(const bf16x8*)(lds + BUF * 32768 + a_rd + mi * 1024);
  #pragma unroll
  for (int ni = 0; ni < 4; ++ni)
    bfr[ni] = *(const bf16x8*)(lds + 65536 + BUF * 32768 + b_rd + (ni & 1) * 1024 + (ni >> 1) * 4096);
  if (ST) {
    load_lds16(aS0 + kn, lds + NB_ + stg);
    load_lds16(aS1 + kn, lds + NB_ + stg + 1024);
  }
  GPHASE_BAR_WAIT();
  __builtin_amdgcn_s_setprio(1);
  #pragma unroll
  for (int mi = 0; mi < 4; ++mi)
    #pragma unroll
    for (int ni = 0; ni < 4; ++ni)
      acc[mi][ni] = __builtin_amdgcn_mfma_f32_16x16x32_bf16(af[mi], bfr[ni], acc[mi][ni], 0, 0, 0);
  __builtin_amdgcn_s_setprio(0);
  __builtin_amdgcn_sched_barrier(0);
  __builtin_amdgcn_s_barrier();
  // ---- P1: k0, rows 64-127; read A; reuse bfr; issue B-k0(t+1) ----
  #pragma unroll
  for (int mi = 0; mi < 4; ++mi)
    af[mi] = *(const bf16x8*)(lds + BUF * 32768 + 4096 + a_rd + mi * 1024);
  if (ST) {
    load_lds16(bS0 + kn, lds + 65536 + NB_ + stg);
    load_lds16(bS1 + kn, lds + 65536 + NB_ + stg + 1024);
  }
  GPHASE_BAR_WAIT();
  __builtin_amdgcn_s_setprio(1);
  #pragma unroll
  for (int mi = 0; mi < 4; ++mi)
    #pragma unroll
    for (int ni = 0; ni < 4; ++ni)
      acc[4 + mi][ni] = __builtin_amdgcn_mfma_f32_16x16x32_bf16(af[mi], bfr[ni], acc[4 + mi][ni], 0, 0, 0);
  __builtin_amdgcn_s_setprio(0);
  __builtin_amdgcn_sched_barrier(0);
  if (ST) asm volatile("s_waitcnt vmcnt(4)" ::: "memory");
  else    asm volatile("s_waitcnt vmcnt(0)" ::: "memory");
  __builtin_amdgcn_s_barrier();
  // ---- P2: k1, rows 0-63; read A+B; issue A-k1(t+1) ----
  #pragma unroll
  for (int mi = 0; mi < 4; ++mi)
    af[mi] = *(const bf16x8*)(lds + BUF * 32768 + 16384 + a_rd + mi * 1024);
  #pragma unroll
  for (int ni = 0; ni < 4; ++ni)
    bfr[ni] = *(const bf16x8*)(lds + 65536 + BUF * 32768 + 16384 + b_rd + (ni & 1) * 1024 + (ni >> 1) * 4096);
  if (ST) {
    load_lds16(aS0 + kn + 32, lds + NB_ + 16384 + stg);
    load_lds16(aS1 + kn + 32, lds + NB_ + 16384 + stg + 1024);
  }
  GPHASE_BAR_WAIT();
  __builtin_amdgcn_s_setprio(1);
  #pragma unroll
  for (int mi = 0; mi < 4; ++mi)
    #pragma unroll
    for (int ni = 0; ni < 4; ++ni)
      acc[mi][ni] = __builtin_amdgcn_mfma_f32_16x16x32_bf16(af[mi], bfr[ni], acc[mi][ni], 0, 0, 0);
  __builtin_amdgcn_s_setprio(0);
  __builtin_amdgcn_sched_barrier(0);
  __builtin_amdgcn_s_barrier();
  // ---- P3: k1, rows 64-127; reuse bfr; issue B-k1(t+1); end: vmcnt(4)+barrier ----
  #pragma unroll
  for (int mi = 0; mi < 4; ++mi)
    af[mi] = *(const bf16x8*)(lds + BUF * 32768 + 16384 + 4096 + a_rd + mi * 1024);
  if (ST) {
    load_lds16(bS0 + kn + 32, lds + 65536 + NB_ + 16384 + stg);
    load_lds16(bS1 + kn + 32, lds + 65536 + NB_ + 16384 + stg + 1024);
  }
  GPHASE_BAR_WAIT();
  __builtin_amdgcn_s_setprio(1);
  #pragma unroll
  for (int mi = 0; mi < 4; ++mi)
    #pragma unroll
    for (int ni = 0; ni < 4; ++ni)
      acc[4 + mi][ni] = __builtin_amdgcn_mfma_f32_16x16x32_bf16(af[mi], bfr[ni], acc[4 + mi][ni], 0, 0, 0);
  __builtin_amdgcn_s_setprio(0);
  __builtin_amdgcn_sched_barrier(0);
  if (ST) asm volatile("s_waitcnt vmcnt(4)" ::: "memory");
  __builtin_amdgcn_s_barrier();
}

// MODE: 0 = f32 out, 1 = rope + bf16 out, 2 = bf16 out
template<int KTOT, int MODE>
__global__ __launch_bounds__(512, 2) void gemm256_kernel(const unsigned short* __restrict__ A,
    const unsigned short* __restrict__ Bw, void* __restrict__ Cout,
    const float* __restrict__ cosb, const float* __restrict__ sinb) {
  extern __shared__ char lds[];
  const int K = KTOT;
  int tid = threadIdx.x, lane = tid & 63, wave = tid >> 6;
  int wm = wave >> 2, wn = wave & 3;
  int l15 = lane & 15, l16 = lane >> 4;
  int orig = blockIdx.y * 16 + blockIdx.x;
  int swz = (orig & 7) * 32 + (orig >> 3);            // bijective XCD swizzle (256 WGs)
  int bm = (swz >> 4) * 256, bn = (swz & 15) * 256;
  int srA0 = (wave * 2 + 0) * 16 + (lane >> 2);
  int srA1 = (wave * 2 + 1) * 16 + (lane >> 2);
  int scA0 = ((lane & 3) ^ ((srA0 >> 1) & 3)) * 8;
  int scA1 = ((lane & 3) ^ ((srA1 >> 1) & 3)) * 8;
  const unsigned short* aS0 = A + (size_t)(bm + srA0) * K + scA0;
  const unsigned short* aS1 = A + (size_t)(bm + srA1) * K + scA1;
  const unsigned short* bS0 = Bw + (size_t)(bn + srA0) * K + scA0;
  const unsigned short* bS1 = Bw + (size_t)(bn + srA1) * K + scA1;
  int stg = wave * 2048 + lane * 16;
  int rslot = (l16 ^ ((l15 >> 1) & 3)) * 16;
  int a_rd = (wm * 128 + l15) * 64 + rslot;
  int wcbase = (wn >> 1) * 128 + (wn & 1) * 32;       // wave's col base within 256-tile
  int b_rd = (wcbase + l15) * 64 + rslot;
  f32x4 acc[8][4];
  const f32x4 fz = {0.f, 0.f, 0.f, 0.f};
  #pragma unroll
  for (int i = 0; i < 8; ++i)
    #pragma unroll
    for (int j = 0; j < 4; ++j) acc[i][j] = fz;
  load_lds16(aS0, lds + stg);
  load_lds16(aS1, lds + stg + 1024);
  load_lds16(bS0, lds + 65536 + stg);
  load_lds16(bS1, lds + 65536 + stg + 1024);
  load_lds16(aS0 + 32, lds + 16384 + stg);
  load_lds16(aS1 + 32, lds + 16384 + stg + 1024);
  load_lds16(bS0 + 32, lds + 65536 + 16384 + stg);
  load_lds16(bS1 + 32, lds + 65536 + 16384 + stg + 1024);
  asm volatile("s_waitcnt vmcnt(4)" ::: "memory");
  __builtin_amdgcn_s_barrier();
  for (int tt = 0; tt < KTOT / 128 - 1; ++tt) {
    ktile<0, true>(lds, acc, a_rd, b_rd, aS0, aS1, bS0, bS1, stg, (2 * tt + 1) * 64);
    ktile<1, true>(lds, acc, a_rd, b_rd, aS0, aS1, bS0, bS1, stg, (2 * tt + 2) * 64);
  }
  ktile<0, true>(lds, acc, a_rd, b_rd, aS0, aS1, bS0, bS1, stg, (KTOT / 64 - 1) * 64);
  ktile<1, false>(lds, acc, a_rd, b_rd, aS0, aS1, bS0, bS1, stg, 0);

  if (MODE == 0) {
    float* C = (float*)Cout;
    #pragma unroll
    for (int mi = 0; mi < 8; ++mi) {
      int gr = bm + wm * 128 + mi * 16 + l16 * 4;
      #pragma unroll
      for (int ni = 0; ni < 4; ++ni) {
        int gc = bn + wcbase + (ni & 1) * 16 + (ni >> 1) * 64 + l15;
        #pragma unroll
        for (int r = 0; r < 4; ++r)
          C[(size_t)(gr + r) * HIDN + gc] = acc[mi][ni][r];
      }
    }
  } else if (MODE == 2) {
    unsigned short* O = (unsigned short*)Cout;
    #pragma unroll
    for (int mi = 0; mi < 8; ++mi) {
      int gr = bm + wm * 128 + mi * 16 + l16 * 4;
      #pragma unroll
      for (int ni = 0; ni < 4; ++ni) {
        int gc = bn + wcbase + (ni & 1) * 16 + (ni >> 1) * 64 + l15;
        #pragma unroll
        for (int r = 0; r < 4; ++r)
          O[(size_t)(gr + r) * HIDN + gc] = f2bf(acc[mi][ni][r]);
      }
    }
  } else {
    unsigned short* O = (unsigned short*)Cout;
    #pragma unroll
    for (int mi = 0; mi < 8; ++mi) {
      int gr = bm + wm * 128 + mi * 16 + l16 * 4;
      #pragma unroll
      for (int p = 0; p < 2; ++p) {                    // pair (p, p+2): cols jj and jj+64
        int jj = (wn & 1) * 32 + p * 16 + l15;         // in-head rotary index, < 64
        int gclo = bn + wcbase + p * 16 + l15;
        #pragma unroll
        for (int r = 0; r < 4; ++r) {
          int row = gr + r;
          int s = row & (SEQL - 1);
          float cs = cosb[s * 64 + jj];
          float sn = sinb[s * 64 + jj];
          float lo = acc[mi][p][r], hi = acc[mi][p + 2][r];
          O[(size_t)row * HIDN + gclo] = f2bf(lo * cs - hi * sn);
          O[(size_t)row * HIDN + gclo + 64] = f2bf(hi * cs + lo * sn);
        }
      }
    }
  }
}

// ---------------- split-K (x8) skinny GEMM (A stride Ka, B stride HIDN) ----------------
__global__ __launch_bounds__(256) void gemm_bt_splitk_kernel(const unsigned short* __restrict__ A,
    const unsigned short* __restrict__ Bw, float* __restrict__ Cp, int N, int Ka) {
  __shared__ __align__(16) unsigned short As[128][32];
  __shared__ __align__(16) unsigned short Bs[128][32];
  const int KSPAN = 512;
  int tid = threadIdx.x;
  int lane = tid & 63, wave = tid >> 6;
  int bm = blockIdx.y * 128, bn = blockIdx.x * 128;
  int k0 = blockIdx.z * KSPAN;
  int wr = (wave >> 1) * 64, wc = (wave & 1) * 64;
  const f32x4 fz = {0.f, 0.f, 0.f, 0.f};
  f32x4 acc[4][4];
  #pragma unroll
  for (int i = 0; i < 4; ++i)
    #pragma unroll
    for (int j = 0; j < 4; ++j) acc[i][j] = fz;
  const unsigned short* a0 = A + (size_t)(bm + (tid >> 2)) * Ka + (tid & 3) * 8 + k0;
  const unsigned short* b0 = Bw + (size_t)(bn + (tid >> 2)) * HIDN + (tid & 3) * 8 + k0;
  char* lA = (char*)&As[0][0] + wave * 1024;
  char* lB = (char*)&Bs[0][0] + wave * 1024;
  int l15 = lane & 15, l4 = (lane >> 4) * 8;
  for (int kt = 0; kt < KSPAN; kt += 32) {
    load_lds16(a0 + kt, lA);
    load_lds16(a0 + kt + (size_t)64 * Ka, lA + 4096);
    load_lds16(b0 + kt, lB);
    load_lds16(b0 + kt + (size_t)64 * HIDN, lB + 4096);
    __syncthreads();
    bf16x8 af[4], bfr[4];
    #pragma unroll
    for (int mi = 0; mi < 4; ++mi) af[mi] = *(const bf16x8*)&As[wr + mi * 16 + l15][l4];
    #pragma unroll
    for (int ni = 0; ni < 4; ++ni) bfr[ni] = *(const bf16x8*)&Bs[wc + ni * 16 + l15][l4];
    #pragma unroll
    for (int mi = 0; mi < 4; ++mi)
      #pragma unroll
      for (int ni = 0; ni < 4; ++ni)
        acc[mi][ni] = __builtin_amdgcn_mfma_f32_16x16x32_bf16(af[mi], bfr[ni], acc[mi][ni], 0, 0, 0);
    __syncthreads();
  }
  float* Cz = Cp + (size_t)blockIdx.z * TTOK * N;
  #pragma unroll
  for (int mi = 0; mi < 4; ++mi) {
    int r0 = bm + wr + mi * 16 + (lane >> 4) * 4;
    #pragma unroll
    for (int ni = 0; ni < 4; ++ni) {
      int c = bn + wc + ni * 16 + l15;
      #pragma unroll
      for (int r = 0; r < 4; ++r)
        Cz[(size_t)(r0 + r) * N + c] = acc[mi][ni][r];
    }
  }
}

// ---------------- reduce 8 split-K partials ----------------
__global__ __launch_bounds__(256) void reduce8_kernel(const float* __restrict__ Cp,
                                                      float* __restrict__ C, int n) {
  int i = (blockIdx.x * 256 + threadIdx.x) * 4;
  float4 s = *(const float4*)(Cp + i);
  #pragma unroll
  for (int z = 1; z < 8; ++z) {
    float4 v = *(const float4*)(Cp + (size_t)z * n + i);
    s.x += v.x; s.y += v.y; s.z += v.z; s.w += v.w;
  }
  *(float4*)(C + i) = s;
}

// ---------------- flash attention: raw barriers (no vmcnt(0) drain) + V 2-ahead ----------------
#define ATTN_STEP(T, CUR, W0, W1, L0, L1)                                              \
  {                                                                                    \
    const int haveK = (T) + 32 < kend;                                                 \
    const int haveV2 = (T) + 64 < kend;                                                \
    if (haveK) {                                                                       \
      char* lKn = (CUR) ? lK0 : lK1;                                                   \
      load_lds16(kgbase + (size_t)((T) + 32) * HIDN, lKn);                             \
      load_lds16(kgbase + (size_t)((T) + 48) * HIDN, lKn + 4096);                      \
    }                                                                                  \
    __builtin_amdgcn_sched_barrier(0);                                                 \
    if (haveV2) {                                                                      \
      const unsigned short* vg = vgbase + (size_t)((T) + 64 + vks0 * 8) * HIDN;        \
      for (int j = 0; j < 8; ++j) L0[j] = (short)vg[(size_t)j * HIDN];                 \
      for (int j = 0; j < 8; ++j) L1[j] = (short)vg[(size_t)(8 + j) * HIDN];           \
    }                                                                                  \
    __builtin_amdgcn_sched_barrier(0);                                                 \
    const char* ksb = (const char*)&Ks[CUR][0][0];                                     \
    f32x4 sacc[2] = {fz, fz};                                                          \
    for (int ks = 0; ks < 4; ++ks) {                                                   \
      for (int nf = 0; nf < 2; ++nf) {                                                 \
        int row = nf * 16 + l15;                                                       \
        int slot = (ks * 4 + l16) ^ (l15 & 7);                                         \
        bf16x8 kf = *(const bf16x8*)(ksb + row * 256 + slot * 16);                     \
        sacc[nf] = __builtin_amdgcn_mfma_f32_16x16x32_bf16(qf[ks], kf, sacc[nf], 0, 0, 0); \
      }                                                                                \
    }                                                                                  \
    if ((T) + 31 <= q0 + wave * 16) {                                                  \
      for (int rr = 0; rr < 4; ++rr) {                                                 \
        float e0 = __expf(SCALEF * sacc[0][rr]);                                       \
        float e1 = __expf(SCALEF * sacc[1][rr]);                                       \
        Ps[wave][l16 * 4 + rr][l15] = f2bf(e0);                                        \
        Ps[wave][l16 * 4 + rr][16 + l15] = f2bf(e1);                                   \
      }                                                                                \
    } else {                                                                           \
      for (int rr = 0; rr < 4; ++rr) {                                                 \
        int qr = q0 + wave * 16 + l16 * 4 + rr;                                        \
        float e0 = ((T) + l15 > qr) ? 0.f : __expf(SCALEF * sacc[0][rr]);              \
        float e1 = ((T) + 16 + l15 > qr) ? 0.f : __expf(SCALEF * sacc[1][rr]);         \
        Ps[wave][l16 * 4 + rr][l15] = f2bf(e0);                                        \
        Ps[wave][l16 * 4 + rr][16 + l15] = f2bf(e1);                                   \
      }                                                                                \
    }                                                                                  \
    bf16x8 pf = *(const bf16x8*)&Ps[wave][l15][l16 * 8];                               \
    sumac = __builtin_amdgcn_mfma_f32_16x16x32_bf16(pf, ones, sumac, 0, 0, 0);         \
    for (int nf = 0; nf < 8; ++nf) {                                                   \
      bf16x8 vf = *(const bf16x8*)((const char*)&Vt[0][0] + (nf * 16 + l15) * 80 + l16 * 16); \
      oacc[nf] = __builtin_amdgcn_mfma_f32_16x16x32_bf16(pf, vf, oacc[nf], 0, 0, 0);   \
    }                                                                                  \
    asm volatile("s_waitcnt lgkmcnt(0)\n\ts_barrier" ::: "memory");                    \
    if (haveK) {                                                                       \
      *(bf16x8*)vtp = W0;                                                              \
      *(bf16x8*)(vtp + 16) = W1;                                                       \
    }                                                                                  \
    if (haveV2)                                                                        \
      asm volatile("s_waitcnt lgkmcnt(0) vmcnt(16)\n\ts_barrier" ::: "memory");        \
    else if (haveK)                                                                    \
      asm volatile("s_waitcnt lgkmcnt(0) vmcnt(0)\n\ts_barrier" ::: "memory");         \
    else                                                                               \
      asm volatile("s_waitcnt lgkmcnt(0)\n\ts_barrier" ::: "memory");                  \
  }

__global__ __launch_bounds__(256) void attn_kernel(const unsigned short* __restrict__ qb,
    const unsigned short* __restrict__ kb, const unsigned short* __restrict__ vb,
    unsigned short* __restrict__ ob) {
  __shared__ __align__(16) unsigned short Ks[2][32][128];
  __shared__ __align__(16) unsigned short Vt[128][40];
  __shared__ __align__(16) unsigned short Ps[4][16][40];
  int tid = threadIdx.x, lane = tid & 63, wave = tid >> 6;
  int id = blockIdx.y * gridDim.x + blockIdx.x;   // gridDim.x = 8, 2048 blocks
  int xcd = id & 7, w = id >> 3;                  // w in [0,256)
  int bh = xcd * 16 + (w & 15);
  int qt = 15 - (w >> 4);                         // longest blocks dispatch first
  int b = bh >> 5, h = bh & 31;
  size_t base = ((size_t)b * SEQL) * HIDN + (size_t)h * 128;
  size_t obase = ((size_t)b * SEQL) * KEXT + (size_t)h * 128;
  int l15 = lane & 15, l16 = lane >> 4;
  int krow = tid >> 4;
  int kslot = (tid & 15) ^ (krow & 7);
  const unsigned short* kgbase = kb + base + (size_t)krow * HIDN + kslot * 8;
  char* lK0 = (char*)&Ks[0][0][0] + wave * 1024;
  char* lK1 = (char*)&Ks[1][0][0] + wave * 1024;
  int vd = tid >> 1;
  int vks0 = (tid & 1) * 2;
  const unsigned short* vgbase = vb + base + vd;
  char* vtp = (char*)&Vt[0][0] + vd * 80 + vks0 * 16;
  const f32x4 fz = {0.f, 0.f, 0.f, 0.f};
  const short ONEBF = (short)0x3F80;
  const bf16x8 ones = {ONEBF, ONEBF, ONEBF, ONEBF, ONEBF, ONEBF, ONEBF, ONEBF};

  int q0 = qt * 64;
  int kend = q0 + 64;                             // always a multiple of 64
  int qrow = q0 + wave * 16 + l15;
  const unsigned short* qrp = qb + base + (size_t)qrow * HIDN + l16 * 8;
  bf16x8 qf[4];
  #pragma unroll
  for (int ks = 0; ks < 4; ++ks) qf[ks] = *(const bf16x8*)(qrp + ks * 32);
  f32x4 oacc[8];
  #pragma unroll
  for (int i = 0; i < 8; ++i) oacc[i] = fz;
  f32x4 sumac = fz;
  load_lds16(kgbase, lK0);
  load_lds16(kgbase + (size_t)16 * HIDN, lK0 + 4096);
  {
    bf16x8 v0, v1;
    const unsigned short* vg = vgbase + (size_t)(vks0 * 8) * HIDN;
    #pragma unroll
    for (int j = 0; j < 8; ++j) v0[j] = (short)vg[(size_t)j * HIDN];
    #pragma unroll
    for (int j = 0; j < 8; ++j) v1[j] = (short)vg[(size_t)(8 + j) * HIDN];
    *(bf16x8*)vtp = v0;
    *(bf16x8*)(vtp + 16) = v1;
  }
  bf16x8 nA0, nA1, nB0, nB1;
  {
    const unsigned short* vg = vgbase + (size_t)(32 + vks0 * 8) * HIDN;
    #pragma unroll
    for (int j = 0; j < 8; ++j) nA0[j] = (short)vg[(size_t)j * HIDN];
    #pragma unroll
    for (int j = 0; j < 8; ++j) nA1[j] = (short)vg[(size_t)(8 + j) * HIDN];
  }
  __syncthreads();
  for (int kt = 0; kt < kend; kt += 64) {
    ATTN_STEP(kt, 0, nA0, nA1, nB0, nB1);
    ATTN_STEP(kt + 32, 1, nB0, nB1, nA0, nA1);
  }
  #pragma unroll
  for (int rr = 0; rr < 4; ++rr) {
    int qr = q0 + wave * 16 + l16 * 4 + rr;
    float inv = 1.0f / sumac[rr];
    unsigned short* orow = ob + obase + (size_t)qr * KEXT;
    #pragma unroll
    for (int nf = 0; nf < 8; ++nf)
      orow[nf * 16 + l15] = f2bf(oacc[nf][rr] * inv);
  }
}

extern "C" void kernel_launch(void* const* d_in, const int* in_sizes, int n_in,
                              void* d_out, int out_size, void* d_ws, size_t ws_size,
                              hipStream_t stream) {
  (void)in_sizes; (void)n_in; (void)out_size; (void)ws_size;
  const float* x = (const float*)d_in[0];
  const int* lidx = (const int*)d_in[1];
  const float* W[4] = {(const float*)d_in[2], (const float*)d_in[3],
                       (const float*)d_in[4], (const float*)d_in[5]};
  const float* wa_q = (const float*)d_in[6];
  const float* wb_q = (const float*)d_in[7];
  const float* wa_k = (const float*)d_in[8];
  const float* wb_k = (const float*)d_in[9];
  const float* wa_v = (const float*)d_in[10];
  const float* wb_v = (const float*)d_in[11];
  const float* wa_o = (const float*)d_in[12];
  const float* wb_o = (const float*)d_in[13];
  float* out = (float*)d_out;

  char* p = (char*)d_ws;
  unsigned short* Xext = (unsigned short*)p;  p += (size_t)TTOK * KEXT * 2;
  unsigned short* Wext = (unsigned short*)p;  p += (size_t)HIDN * KEXT * 2;
  float* tmp = (float*)p;                     p += (size_t)TTOK * HIDN * 4;
  unsigned short* qbuf = (unsigned short*)p;  p += (size_t)TTOK * HIDN * 2;
  unsigned short* kbuf = (unsigned short*)p;  p += (size_t)TTOK * HIDN * 2;
  unsigned short* vbuf = (unsigned short*)p;  p += (size_t)TTOK * HIDN * 2;
  unsigned short* Aext = (unsigned short*)p;  p += (size_t)TTOK * KEXT * 2;
  unsigned short* WAbf = (unsigned short*)p;  p += (size_t)384 * HIDN * 2;
  float* afull = (float*)p;                   p += (size_t)TTOK * 384 * 4;
  float* aofull = (float*)p;                  p += (size_t)TTOK * 128 * 4;
  float* cosb = (float*)p;                    p += (size_t)SEQL * 64 * 4;
  float* sinb = (float*)p;                    p += (size_t)SEQL * 64 * 4;

  const int CVT_BLOCKS = (TTOK * HIDN) / 1024;
  const int CVT_WA = (128 * HIDN) / 1024;
  const int CONVW_BLOCKS = CVT_BLOCKS + (HIDN * 32) / 256;   // 16384 + 512
  dim3 g256(16, 16);

  hipFuncSetAttribute((const void*)gemm256_kernel<KEXT, 0>,
                      hipFuncAttributeMaxDynamicSharedMemorySize, 131072);
  hipFuncSetAttribute((const void*)gemm256_kernel<KEXT, 1>,
                      hipFuncAttributeMaxDynamicSharedMemorySize, 131072);
  hipFuncSetAttribute((const void*)gemm256_kernel<KEXT, 2>,
                      hipFuncAttributeMaxDynamicSharedMemorySize, 131072);

  rope_tab_kernel<<<(SEQL * 64) / 256, 256, 0, stream>>>(cosb, sinb);
  f2b_pad_kernel<<<CVT_BLOCKS, 256, 0, stream>>>(x, Xext);
  conv_wa3_kernel<<<3 * CVT_WA, 256, 0, stream>>>(wa_q, wa_k, wa_v, WAbf);
  gemm_bt_splitk_kernel<<<dim3(3, 32, 8), 256, 0, stream>>>(Xext, WAbf, tmp, 384, KEXT);
  reduce8_kernel<<<(TTOK * 384) / 1024, 256, 0, stream>>>(tmp, afull, TTOK * 384);

  // Q projection: lora-B folded; rope+bf16 fused into gemm epilogue
  conv_w_kernel<<<CONVW_BLOCKS, 256, 0, stream>>>(W[0], wb_q, Wext);
  afat_kernel<<<TTOK, 128, 0, stream>>>(afull, 0, 384, lidx, Xext);
  gemm256_kernel<KEXT, 1><<<g256, 512, 131072, stream>>>(Xext, Wext, qbuf, cosb, sinb);
  // K projection
  conv_w_kernel<<<CONVW_BLOCKS, 256, 0, stream>>>(W[1], wb_k, Wext);
  afat_kernel<<<TTOK, 128, 0, stream>>>(afull, 128, 384, lidx, Xext);
  gemm256_kernel<KEXT, 1><<<g256, 512, 131072, stream>>>(Xext, Wext, kbuf, cosb, sinb);
  // V projection (no rope: fused bf16 cast)
  conv_w_kernel<<<CONVW_BLOCKS, 256, 0, stream>>>(W[2], wb_v, Wext);
  afat_kernel<<<TTOK, 128, 0, stream>>>(afull, 256, 384, lidx, Xext);
  gemm256_kernel<KEXT, 2><<<g256, 512, 131072, stream>>>(Xext, Wext, vbuf, nullptr, nullptr);

  attn_kernel<<<dim3(8, 256), 256, 0, stream>>>(qbuf, kbuf, vbuf, Aext);

  // output projection: lora-A on attention output, then fused gemm -> out directly
  f2b_kernel<<<CVT_WA, 256, 0, stream>>>(wa_o, WAbf);
  gemm_bt_splitk_kernel<<<dim3(1, 32, 8), 256, 0, stream>>>(Aext, WAbf, tmp, 128, KEXT);
  reduce8_kernel<<<(TTOK * 128) / 1024, 256, 0, stream>>>(tmp, aofull, TTOK * 128);
  conv_w_kernel<<<CONVW_BLOCKS, 256, 0, stream>>>(W[3], wb_o, Wext);
  afat_kernel<<<TTOK, 128, 0, stream>>>(aofull, 0, 128, lidx, Aext);
  gemm256_kernel<KEXT, 0><<<g256, 512, 131072, stream>>>(Aext, Wext, out, nullptr, nullptr);
}

// Round 14
// 788.459 us; speedup vs baseline: 1.0119x; 1.0119x over previous
//
#include <hip/hip_runtime.h>

#define HIDN 4096
#define KEXT 4224
#define TTOK 4096
#define SEQL 1024
#define NB 4
#define NHEAD 32
#define SCALEF 0.08838834764831845f

typedef __attribute__((ext_vector_type(8))) short bf16x8;
typedef __attribute__((ext_vector_type(8))) unsigned short u16x8;
typedef __attribute__((ext_vector_type(4))) float f32x4;

static __device__ __forceinline__ unsigned short f2bf(float f) {
  union { float f; unsigned u; } v; v.f = f;
  unsigned r = v.u + 0x7fffu + ((v.u >> 16) & 1u);
  return (unsigned short)(r >> 16);
}
static __device__ __forceinline__ void load_lds16(const void* g, void* l) {
  __builtin_amdgcn_global_load_lds((const __attribute__((address_space(1))) void*)g,
                                   (__attribute__((address_space(3))) void*)l, 16, 0, 0);
}

// ---------------- fp32 -> bf16 cast (contiguous): grid = n/1024 blocks ----------------
__global__ __launch_bounds__(256) void f2b_kernel(const float* __restrict__ s,
                                                  unsigned short* __restrict__ d) {
  size_t i = ((size_t)blockIdx.x * 256 + threadIdx.x) * 4;
  float4 v = *(const float4*)(s + i);
  ushort4 o;
  o.x = f2bf(v.x); o.y = f2bf(v.y); o.z = f2bf(v.z); o.w = f2bf(v.w);
  *(ushort4*)(d + i) = o;
}

// ---------------- fp32 [R][4096] -> bf16 dst[R][KEXT] cols 0..4095 ----------------
__global__ __launch_bounds__(256) void f2b_pad_kernel(const float* __restrict__ s,
                                                      unsigned short* __restrict__ d) {
  size_t i = ((size_t)blockIdx.x * 256 + threadIdx.x) * 4;
  int row = (int)(i >> 12);
  int col = (int)(i & 4095);
  float4 v = *(const float4*)(s + i);
  ushort4 o;
  o.x = f2bf(v.x); o.y = f2bf(v.y); o.z = f2bf(v.z); o.w = f2bf(v.w);
  *(ushort4*)(d + (size_t)row * KEXT + col) = o;
}

// ---------------- merged: W pad-cast + wb fold into Wext ----------------
__global__ __launch_bounds__(256) void conv_w_kernel(const float* __restrict__ W,
    const float* __restrict__ wb, unsigned short* __restrict__ wext) {
  int bid = blockIdx.x;
  if (bid < 16384) {
    size_t i = ((size_t)bid * 256 + threadIdx.x) * 4;
    int row = (int)(i >> 12);
    int col = (int)(i & 4095);
    float4 v = *(const float4*)(W + i);
    ushort4 o;
    o.x = f2bf(v.x); o.y = f2bf(v.y); o.z = f2bf(v.z); o.w = f2bf(v.w);
    *(ushort4*)(wext + (size_t)row * KEXT + col) = o;
  } else {
    int idx = (bid - 16384) * 256 + threadIdx.x;
    int o = idx >> 5;
    int j4 = (idx & 31) * 4;
    int l = j4 >> 4, r = j4 & 15;
    float4 v = *(const float4*)(wb + ((size_t)l * HIDN + o) * 16 + r);
    ushort4 q;
    q.x = f2bf(v.x); q.y = f2bf(v.y); q.z = f2bf(v.z); q.w = f2bf(v.w);
    *(ushort4*)(wext + (size_t)o * KEXT + 4096 + j4) = q;
  }
}

// ---------------- merged: three wa tensors -> WAbf in one launch ----------------
__global__ __launch_bounds__(256) void conv_wa3_kernel(const float* __restrict__ s0,
    const float* __restrict__ s1, const float* __restrict__ s2,
    unsigned short* __restrict__ d) {
  int sel = blockIdx.x >> 9;
  const float* s = (sel == 0) ? s0 : ((sel == 1) ? s1 : s2);
  size_t i = ((size_t)(blockIdx.x & 511) * 256 + threadIdx.x) * 4;
  float4 v = *(const float4*)(s + i);
  ushort4 o;
  o.x = f2bf(v.x); o.y = f2bf(v.y); o.z = f2bf(v.z); o.w = f2bf(v.w);
  *(ushort4*)(d + (size_t)sel * 128 * HIDN + i) = o;
}

// ---------------- Afat: one-hot-expanded lora activations -> Xext cols 4096..4223 ----------------
__global__ __launch_bounds__(128) void afat_kernel(const float* __restrict__ afull, int aoff,
    int awidth, const int* __restrict__ lidx, unsigned short* __restrict__ xext) {
  int t = blockIdx.x, j = threadIdx.x;
  int l = lidx[t];
  float v = afull[(size_t)t * awidth + aoff + j];
  unsigned short o = ((j >> 4) == l) ? f2bf(v) : (unsigned short)0;
  xext[(size_t)t * KEXT + 4096 + j] = o;
}

// ---------------- rope tables ----------------
__global__ __launch_bounds__(256) void rope_tab_kernel(float* __restrict__ cosb,
                                                       float* __restrict__ sinb) {
  int i = blockIdx.x * 256 + threadIdx.x;
  int s = i >> 6, j = i & 63;
  float inv = __expf(-__logf(10000.0f) * (float)j * (1.0f / 64.0f));
  float f = (float)s * inv;
  cosb[i] = cosf(f);
  sinb[i] = sinf(f);
}

// =================== 256x256 GEMM, k-sliced planes + counted vmcnt (R12 optimum) ===================
// Per K-tile (BK=64): P0(k0,m0)+issue A-k0(t+1) | P1(k0,m1)+issue B-k0(t+1) | vmcnt(4)+bar |
// P2(k1,m0)+issue A-k1(t+1) | P3(k1,m1)+issue B-k1(t+1) | vmcnt(4)+bar. Never drains to 0.
// B frags read once per k-half (P0/P2), reused in P1/P3.
// NOTE (R8/R13 post-mortems): issue-early staging w/ deeper vmcnt AND per-phase barrier
// convoy BOTH regressed vs this schedule — it is the empirical optimum for this layout.
template<int BUF, bool ST>
__device__ __forceinline__ void ktile(char* lds, f32x4 (&acc)[8][4], int a_rd, int b_rd,
    const unsigned short* aS0, const unsigned short* aS1,
    const unsigned short* bS0, const unsigned short* bS1, int stg, int kn) {
  const int NB_ = (BUF ^ 1) * 32768;
  bf16x8 bfr[4];
  // P0: k0, rows 0-63; read B frags (once for P0+P1); issue A-k0(t+1)
  {
    __builtin_amdgcn_sched_barrier(0);
    bf16x8 af[4];
    #pragma unroll
    for (int mi = 0; mi < 4; ++mi)
      af[mi] = *(const bf16x8*)(lds + BUF * 32768 + a_rd + mi * 1024);
    #pragma unroll
    for (int ni = 0; ni < 4; ++ni)
      bfr[ni] = *(const bf16x8*)(lds + 65536 + BUF * 32768 + b_rd + (ni & 1) * 1024 + (ni >> 1) * 4096);
    if (ST) {
      load_lds16(aS0 + kn, lds + NB_ + stg);
      load_lds16(aS1 + kn, lds + NB_ + stg + 1024);
    }
    __builtin_amdgcn_s_setprio(1);
    #pragma unroll
    for (int mi = 0; mi < 4; ++mi)
      #pragma unroll
      for (int ni = 0; ni < 4; ++ni)
        acc[mi][ni] = __builtin_amdgcn_mfma_f32_16x16x32_bf16(af[mi], bfr[ni], acc[mi][ni], 0, 0, 0);
    __builtin_amdgcn_s_setprio(0);
  }
  // P1: k0, rows 64-127; reuse bfr; issue B-k0(t+1)
  {
    __builtin_amdgcn_sched_barrier(0);
    bf16x8 af[4];
    #pragma unroll
    for (int mi = 0; mi < 4; ++mi)
      af[mi] = *(const bf16x8*)(lds + BUF * 32768 + 4096 + a_rd + mi * 1024);
    if (ST) {
      load_lds16(bS0 + kn, lds + 65536 + NB_ + stg);
      load_lds16(bS1 + kn, lds + 65536 + NB_ + stg + 1024);
    }
    __builtin_amdgcn_s_setprio(1);
    #pragma unroll
    for (int mi = 0; mi < 4; ++mi)
      #pragma unroll
      for (int ni = 0; ni < 4; ++ni)
        acc[4 + mi][ni] = __builtin_amdgcn_mfma_f32_16x16x32_bf16(af[mi], bfr[ni], acc[4 + mi][ni], 0, 0, 0);
    __builtin_amdgcn_s_setprio(0);
  }
  if (ST) asm volatile("s_waitcnt vmcnt(4)" ::: "memory");
  else    asm volatile("s_waitcnt vmcnt(0)" ::: "memory");
  __builtin_amdgcn_s_barrier();
  // P2: k1, rows 0-63; read B frags; issue A-k1(t+1)
  {
    __builtin_amdgcn_sched_barrier(0);
    bf16x8 af[4];
    #pragma unroll
    for (int mi = 0; mi < 4; ++mi)
      af[mi] = *(const bf16x8*)(lds + BUF * 32768 + 16384 + a_rd + mi * 1024);
    #pragma unroll
    for (int ni = 0; ni < 4; ++ni)
      bfr[ni] = *(const bf16x8*)(lds + 65536 + BUF * 32768 + 16384 + b_rd + (ni & 1) * 1024 + (ni >> 1) * 4096);
    if (ST) {
      load_lds16(aS0 + kn + 32, lds + NB_ + 16384 + stg);
      load_lds16(aS1 + kn + 32, lds + NB_ + 16384 + stg + 1024);
    }
    __builtin_amdgcn_s_setprio(1);
    #pragma unroll
    for (int mi = 0; mi < 4; ++mi)
      #pragma unroll
      for (int ni = 0; ni < 4; ++ni)
        acc[mi][ni] = __builtin_amdgcn_mfma_f32_16x16x32_bf16(af[mi], bfr[ni], acc[mi][ni], 0, 0, 0);
    __builtin_amdgcn_s_setprio(0);
  }
  // P3: k1, rows 64-127; reuse bfr; issue B-k1(t+1)
  {
    __builtin_amdgcn_sched_barrier(0);
    bf16x8 af[4];
    #pragma unroll
    for (int mi = 0; mi < 4; ++mi)
      af[mi] = *(const bf16x8*)(lds + BUF * 32768 + 16384 + 4096 + a_rd + mi * 1024);
    if (ST) {
      load_lds16(bS0 + kn + 32, lds + 65536 + NB_ + 16384 + stg);
      load_lds16(bS1 + kn + 32, lds + 65536 + NB_ + 16384 + stg + 1024);
    }
    __builtin_amdgcn_s_setprio(1);
    #pragma unroll
    for (int mi = 0; mi < 4; ++mi)
      #pragma unroll
      for (int ni = 0; ni < 4; ++ni)
        acc[4 + mi][ni] = __builtin_amdgcn_mfma_f32_16x16x32_bf16(af[mi], bfr[ni], acc[4 + mi][ni], 0, 0, 0);
    __builtin_amdgcn_s_setprio(0);
  }
  if (ST) {
    asm volatile("s_waitcnt vmcnt(4)" ::: "memory");
    __builtin_amdgcn_s_barrier();
  }
}

// MODE: 0 = f32 out, 1 = rope + bf16 out, 2 = bf16 out
template<int KTOT, int MODE>
__global__ __launch_bounds__(512, 2) void gemm256_kernel(const unsigned short* __restrict__ A,
    const unsigned short* __restrict__ Bw, void* __restrict__ Cout,
    const float* __restrict__ cosb, const float* __restrict__ sinb) {
  extern __shared__ char lds[];
  const int K = KTOT;
  int tid = threadIdx.x, lane = tid & 63, wave = tid >> 6;
  int wm = wave >> 2, wn = wave & 3;
  int l15 = lane & 15, l16 = lane >> 4;
  int orig = blockIdx.y * 16 + blockIdx.x;
  int swz = (orig & 7) * 32 + (orig >> 3);            // bijective XCD swizzle (256 WGs)
  int bm = (swz >> 4) * 256, bn = (swz & 15) * 256;
  int srA0 = (wave * 2 + 0) * 16 + (lane >> 2);
  int srA1 = (wave * 2 + 1) * 16 + (lane >> 2);
  int scA0 = ((lane & 3) ^ ((srA0 >> 1) & 3)) * 8;
  int scA1 = ((lane & 3) ^ ((srA1 >> 1) & 3)) * 8;
  const unsigned short* aS0 = A + (size_t)(bm + srA0) * K + scA0;
  const unsigned short* aS1 = A + (size_t)(bm + srA1) * K + scA1;
  const unsigned short* bS0 = Bw + (size_t)(bn + srA0) * K + scA0;
  const unsigned short* bS1 = Bw + (size_t)(bn + srA1) * K + scA1;
  int stg = wave * 2048 + lane * 16;
  int rslot = (l16 ^ ((l15 >> 1) & 3)) * 16;
  int a_rd = (wm * 128 + l15) * 64 + rslot;
  int wcbase = (wn >> 1) * 128 + (wn & 1) * 32;       // wave's col base within 256-tile
  int b_rd = (wcbase + l15) * 64 + rslot;
  f32x4 acc[8][4];
  const f32x4 fz = {0.f, 0.f, 0.f, 0.f};
  #pragma unroll
  for (int i = 0; i < 8; ++i)
    #pragma unroll
    for (int j = 0; j < 4; ++j) acc[i][j] = fz;
  load_lds16(aS0, lds + stg);
  load_lds16(aS1, lds + stg + 1024);
  load_lds16(bS0, lds + 65536 + stg);
  load_lds16(bS1, lds + 65536 + stg + 1024);
  load_lds16(aS0 + 32, lds + 16384 + stg);
  load_lds16(aS1 + 32, lds + 16384 + stg + 1024);
  load_lds16(bS0 + 32, lds + 65536 + 16384 + stg);
  load_lds16(bS1 + 32, lds + 65536 + 16384 + stg + 1024);
  asm volatile("s_waitcnt vmcnt(4)" ::: "memory");
  __builtin_amdgcn_s_barrier();
  for (int tt = 0; tt < KTOT / 128 - 1; ++tt) {
    ktile<0, true>(lds, acc, a_rd, b_rd, aS0, aS1, bS0, bS1, stg, (2 * tt + 1) * 64);
    ktile<1, true>(lds, acc, a_rd, b_rd, aS0, aS1, bS0, bS1, stg, (2 * tt + 2) * 64);
  }
  ktile<0, true>(lds, acc, a_rd, b_rd, aS0, aS1, bS0, bS1, stg, (KTOT / 64 - 1) * 64);
  ktile<1, false>(lds, acc, a_rd, b_rd, aS0, aS1, bS0, bS1, stg, 0);

  if (MODE == 0) {
    float* C = (float*)Cout;
    #pragma unroll
    for (int mi = 0; mi < 8; ++mi) {
      int gr = bm + wm * 128 + mi * 16 + l16 * 4;
      #pragma unroll
      for (int ni = 0; ni < 4; ++ni) {
        int gc = bn + wcbase + (ni & 1) * 16 + (ni >> 1) * 64 + l15;
        #pragma unroll
        for (int r = 0; r < 4; ++r)
          C[(size_t)(gr + r) * HIDN + gc] = acc[mi][ni][r];
      }
    }
  } else if (MODE == 2) {
    unsigned short* O = (unsigned short*)Cout;
    #pragma unroll
    for (int mi = 0; mi < 8; ++mi) {
      int gr = bm + wm * 128 + mi * 16 + l16 * 4;
      #pragma unroll
      for (int ni = 0; ni < 4; ++ni) {
        int gc = bn + wcbase + (ni & 1) * 16 + (ni >> 1) * 64 + l15;
        #pragma unroll
        for (int r = 0; r < 4; ++r)
          O[(size_t)(gr + r) * HIDN + gc] = f2bf(acc[mi][ni][r]);
      }
    }
  } else {
    unsigned short* O = (unsigned short*)Cout;
    #pragma unroll
    for (int mi = 0; mi < 8; ++mi) {
      int gr = bm + wm * 128 + mi * 16 + l16 * 4;
      #pragma unroll
      for (int p = 0; p < 2; ++p) {                    // pair (p, p+2): cols jj and jj+64
        int jj = (wn & 1) * 32 + p * 16 + l15;         // in-head rotary index, < 64
        int gclo = bn + wcbase + p * 16 + l15;
        #pragma unroll
        for (int r = 0; r < 4; ++r) {
          int row = gr + r;
          int s = row & (SEQL - 1);
          float cs = cosb[s * 64 + jj];
          float sn = sinb[s * 64 + jj];
          float lo = acc[mi][p][r], hi = acc[mi][p + 2][r];
          O[(size_t)row * HIDN + gclo] = f2bf(lo * cs - hi * sn);
          O[(size_t)row * HIDN + gclo + 64] = f2bf(hi * cs + lo * sn);
        }
      }
    }
  }
}

// ---------------- split-K (x8) skinny GEMM (A stride Ka, B stride HIDN) ----------------
__global__ __launch_bounds__(256) void gemm_bt_splitk_kernel(const unsigned short* __restrict__ A,
    const unsigned short* __restrict__ Bw, float* __restrict__ Cp, int N, int Ka) {
  __shared__ __align__(16) unsigned short As[128][32];
  __shared__ __align__(16) unsigned short Bs[128][32];
  const int KSPAN = 512;
  int tid = threadIdx.x;
  int lane = tid & 63, wave = tid >> 6;
  int bm = blockIdx.y * 128, bn = blockIdx.x * 128;
  int k0 = blockIdx.z * KSPAN;
  int wr = (wave >> 1) * 64, wc = (wave & 1) * 64;
  const f32x4 fz = {0.f, 0.f, 0.f, 0.f};
  f32x4 acc[4][4];
  #pragma unroll
  for (int i = 0; i < 4; ++i)
    #pragma unroll
    for (int j = 0; j < 4; ++j) acc[i][j] = fz;
  const unsigned short* a0 = A + (size_t)(bm + (tid >> 2)) * Ka + (tid & 3) * 8 + k0;
  const unsigned short* b0 = Bw + (size_t)(bn + (tid >> 2)) * HIDN + (tid & 3) * 8 + k0;
  char* lA = (char*)&As[0][0] + wave * 1024;
  char* lB = (char*)&Bs[0][0] + wave * 1024;
  int l15 = lane & 15, l4 = (lane >> 4) * 8;
  for (int kt = 0; kt < KSPAN; kt += 32) {
    load_lds16(a0 + kt, lA);
    load_lds16(a0 + kt + (size_t)64 * Ka, lA + 4096);
    load_lds16(b0 + kt, lB);
    load_lds16(b0 + kt + (size_t)64 * HIDN, lB + 4096);
    __syncthreads();
    bf16x8 af[4], bfr[4];
    #pragma unroll
    for (int mi = 0; mi < 4; ++mi) af[mi] = *(const bf16x8*)&As[wr + mi * 16 + l15][l4];
    #pragma unroll
    for (int ni = 0; ni < 4; ++ni) bfr[ni] = *(const bf16x8*)&Bs[wc + ni * 16 + l15][l4];
    #pragma unroll
    for (int mi = 0; mi < 4; ++mi)
      #pragma unroll
      for (int ni = 0; ni < 4; ++ni)
        acc[mi][ni] = __builtin_amdgcn_mfma_f32_16x16x32_bf16(af[mi], bfr[ni], acc[mi][ni], 0, 0, 0);
    __syncthreads();
  }
  float* Cz = Cp + (size_t)blockIdx.z * TTOK * N;
  #pragma unroll
  for (int mi = 0; mi < 4; ++mi) {
    int r0 = bm + wr + mi * 16 + (lane >> 4) * 4;
    #pragma unroll
    for (int ni = 0; ni < 4; ++ni) {
      int c = bn + wc + ni * 16 + l15;
      #pragma unroll
      for (int r = 0; r < 4; ++r)
        Cz[(size_t)(r0 + r) * N + c] = acc[mi][ni][r];
    }
  }
}

// ---------------- reduce 8 split-K partials ----------------
__global__ __launch_bounds__(256) void reduce8_kernel(const float* __restrict__ Cp,
                                                      float* __restrict__ C, int n) {
  int i = (blockIdx.x * 256 + threadIdx.x) * 4;
  float4 s = *(const float4*)(Cp + i);
  #pragma unroll
  for (int z = 1; z < 8; ++z) {
    float4 v = *(const float4*)(Cp + (size_t)z * n + i);
    s.x += v.x; s.y += v.y; s.z += v.z; s.w += v.w;
  }
  *(float4*)(C + i) = s;
}

// ---------------- flash attention: raw barriers (no vmcnt(0) drain) + V 2-ahead ----------------
#define ATTN_STEP(T, CUR, W0, W1, L0, L1)                                              \
  {                                                                                    \
    const int haveK = (T) + 32 < kend;                                                 \
    const int haveV2 = (T) + 64 < kend;                                                \
    if (haveK) {                                                                       \
      char* lKn = (CUR) ? lK0 : lK1;                                                   \
      load_lds16(kgbase + (size_t)((T) + 32) * HIDN, lKn);                             \
      load_lds16(kgbase + (size_t)((T) + 48) * HIDN, lKn + 4096);                      \
    }                                                                                  \
    __builtin_amdgcn_sched_barrier(0);                                                 \
    if (haveV2) {                                                                      \
      const unsigned short* vg = vgbase + (size_t)((T) + 64 + vks0 * 8) * HIDN;        \
      for (int j = 0; j < 8; ++j) L0[j] = (short)vg[(size_t)j * HIDN];                 \
      for (int j = 0; j < 8; ++j) L1[j] = (short)vg[(size_t)(8 + j) * HIDN];           \
    }                                                                                  \
    __builtin_amdgcn_sched_barrier(0);                                                 \
    const char* ksb = (const char*)&Ks[CUR][0][0];                                     \
    f32x4 sacc[2] = {fz, fz};                                                          \
    for (int ks = 0; ks < 4; ++ks) {                                                   \
      for (int nf = 0; nf < 2; ++nf) {                                                 \
        int row = nf * 16 + l15;                                                       \
        int slot = (ks * 4 + l16) ^ (l15 & 7);                                         \
        bf16x8 kf = *(const bf16x8*)(ksb + row * 256 + slot * 16);                     \
        sacc[nf] = __builtin_amdgcn_mfma_f32_16x16x32_bf16(qf[ks], kf, sacc[nf], 0, 0, 0); \
      }                                                                                \
    }                                                                                  \
    if ((T) + 31 <= q0 + wave * 16) {                                                  \
      for (int rr = 0; rr < 4; ++rr) {                                                 \
        float e0 = __expf(SCALEF * sacc[0][rr]);                                       \
        float e1 = __expf(SCALEF * sacc[1][rr]);                                       \
        Ps[wave][l16 * 4 + rr][l15] = f2bf(e0);                                        \
        Ps[wave][l16 * 4 + rr][16 + l15] = f2bf(e1);                                   \
      }                                                                                \
    } else {                                                                           \
      for (int rr = 0; rr < 4; ++rr) {                                                 \
        int qr = q0 + wave * 16 + l16 * 4 + rr;                                        \
        float e0 = ((T) + l15 > qr) ? 0.f : __expf(SCALEF * sacc[0][rr]);              \
        float e1 = ((T) + 16 + l15 > qr) ? 0.f : __expf(SCALEF * sacc[1][rr]);         \
        Ps[wave][l16 * 4 + rr][l15] = f2bf(e0);                                        \
        Ps[wave][l16 * 4 + rr][16 + l15] = f2bf(e1);                                   \
      }                                                                                \
    }                                                                                  \
    bf16x8 pf = *(const bf16x8*)&Ps[wave][l15][l16 * 8];                               \
    sumac = __builtin_amdgcn_mfma_f32_16x16x32_bf16(pf, ones, sumac, 0, 0, 0);         \
    for (int nf = 0; nf < 8; ++nf) {                                                   \
      bf16x8 vf = *(const bf16x8*)((const char*)&Vt[0][0] + (nf * 16 + l15) * 80 + l16 * 16); \
      oacc[nf] = __builtin_amdgcn_mfma_f32_16x16x32_bf16(pf, vf, oacc[nf], 0, 0, 0);   \
    }                                                                                  \
    asm volatile("s_waitcnt lgkmcnt(0)\n\ts_barrier" ::: "memory");                    \
    if (haveK) {                                                                       \
      *(bf16x8*)vtp = W0;                                                              \
      *(bf16x8*)(vtp + 16) = W1;                                                       \
    }                                                                                  \
    if (haveV2)                                                                        \
      asm volatile("s_waitcnt lgkmcnt(0) vmcnt(16)\n\ts_barrier" ::: "memory");        \
    else if (haveK)                                                                    \
      asm volatile("s_waitcnt lgkmcnt(0) vmcnt(0)\n\ts_barrier" ::: "memory");         \
    else                                                                               \
      asm volatile("s_waitcnt lgkmcnt(0)\n\ts_barrier" ::: "memory");                  \
  }

__global__ __launch_bounds__(256) void attn_kernel(const unsigned short* __restrict__ qb,
    const unsigned short* __restrict__ kb, const unsigned short* __restrict__ vb,
    unsigned short* __restrict__ ob) {
  __shared__ __align__(16) unsigned short Ks[2][32][128];
  __shared__ __align__(16) unsigned short Vt[128][40];
  __shared__ __align__(16) unsigned short Ps[4][16][40];
  int tid = threadIdx.x, lane = tid & 63, wave = tid >> 6;
  int id = blockIdx.y * gridDim.x + blockIdx.x;   // gridDim.x = 8, 2048 blocks
  int xcd = id & 7, w = id >> 3;                  // w in [0,256)
  int bh = xcd * 16 + (w & 15);
  int qt = 15 - (w >> 4);                         // longest blocks dispatch first
  int b = bh >> 5, h = bh & 31;
  size_t base = ((size_t)b * SEQL) * HIDN + (size_t)h * 128;
  size_t obase = ((size_t)b * SEQL) * KEXT + (size_t)h * 128;
  int l15 = lane & 15, l16 = lane >> 4;
  int krow = tid >> 4;
  int kslot = (tid & 15) ^ (krow & 7);
  const unsigned short* kgbase = kb + base + (size_t)krow * HIDN + kslot * 8;
  char* lK0 = (char*)&Ks[0][0][0] + wave * 1024;
  char* lK1 = (char*)&Ks[1][0][0] + wave * 1024;
  int vd = tid >> 1;
  int vks0 = (tid & 1) * 2;
  const unsigned short* vgbase = vb + base + vd;
  char* vtp = (char*)&Vt[0][0] + vd * 80 + vks0 * 16;
  const f32x4 fz = {0.f, 0.f, 0.f, 0.f};
  const short ONEBF = (short)0x3F80;
  const bf16x8 ones = {ONEBF, ONEBF, ONEBF, ONEBF, ONEBF, ONEBF, ONEBF, ONEBF};

  int q0 = qt * 64;
  int kend = q0 + 64;                             // always a multiple of 64
  int qrow = q0 + wave * 16 + l15;
  const unsigned short* qrp = qb + base + (size_t)qrow * HIDN + l16 * 8;
  bf16x8 qf[4];
  #pragma unroll
  for (int ks = 0; ks < 4; ++ks) qf[ks] = *(const bf16x8*)(qrp + ks * 32);
  f32x4 oacc[8];
  #pragma unroll
  for (int i = 0; i < 8; ++i) oacc[i] = fz;
  f32x4 sumac = fz;
  load_lds16(kgbase, lK0);
  load_lds16(kgbase + (size_t)16 * HIDN, lK0 + 4096);
  {
    bf16x8 v0, v1;
    const unsigned short* vg = vgbase + (size_t)(vks0 * 8) * HIDN;
    #pragma unroll
    for (int j = 0; j < 8; ++j) v0[j] = (short)vg[(size_t)j * HIDN];
    #pragma unroll
    for (int j = 0; j < 8; ++j) v1[j] = (short)vg[(size_t)(8 + j) * HIDN];
    *(bf16x8*)vtp = v0;
    *(bf16x8*)(vtp + 16) = v1;
  }
  bf16x8 nA0, nA1, nB0, nB1;
  {
    const unsigned short* vg = vgbase + (size_t)(32 + vks0 * 8) * HIDN;
    #pragma unroll
    for (int j = 0; j < 8; ++j) nA0[j] = (short)vg[(size_t)j * HIDN];
    #pragma unroll
    for (int j = 0; j < 8; ++j) nA1[j] = (short)vg[(size_t)(8 + j) * HIDN];
  }
  __syncthreads();
  for (int kt = 0; kt < kend; kt += 64) {
    ATTN_STEP(kt, 0, nA0, nA1, nB0, nB1);
    ATTN_STEP(kt + 32, 1, nB0, nB1, nA0, nA1);
  }
  #pragma unroll
  for (int rr = 0; rr < 4; ++rr) {
    int qr = q0 + wave * 16 + l16 * 4 + rr;
    float inv = 1.0f / sumac[rr];
    unsigned short* orow = ob + obase + (size_t)qr * KEXT;
    #pragma unroll
    for (int nf = 0; nf < 8; ++nf)
      orow[nf * 16 + l15] = f2bf(oacc[nf][rr] * inv);
  }
}

extern "C" void kernel_launch(void* const* d_in, const int* in_sizes, int n_in,
                              void* d_out, int out_size, void* d_ws, size_t ws_size,
                              hipStream_t stream) {
  (void)in_sizes; (void)n_in; (void)out_size; (void)ws_size;
  const float* x = (const float*)d_in[0];
  const int* lidx = (const int*)d_in[1];
  const float* W[4] = {(const float*)d_in[2], (const float*)d_in[3],
                       (const float*)d_in[4], (const float*)d_in[5]};
  const float* wa_q = (const float*)d_in[6];
  const float* wb_q = (const float*)d_in[7];
  const float* wa_k = (const float*)d_in[8];
  const float* wb_k = (const float*)d_in[9];
  const float* wa_v = (const float*)d_in[10];
  const float* wb_v = (const float*)d_in[11];
  const float* wa_o = (const float*)d_in[12];
  const float* wb_o = (const float*)d_in[13];
  float* out = (float*)d_out;

  char* p = (char*)d_ws;
  unsigned short* Xext = (unsigned short*)p;  p += (size_t)TTOK * KEXT * 2;
  unsigned short* Wext = (unsigned short*)p;  p += (size_t)HIDN * KEXT * 2;
  float* tmp = (float*)p;                     p += (size_t)TTOK * HIDN * 4;
  unsigned short* qbuf = (unsigned short*)p;  p += (size_t)TTOK * HIDN * 2;
  unsigned short* kbuf = (unsigned short*)p;  p += (size_t)TTOK * HIDN * 2;
  unsigned short* vbuf = (unsigned short*)p;  p += (size_t)TTOK * HIDN * 2;
  unsigned short* Aext = (unsigned short*)p;  p += (size_t)TTOK * KEXT * 2;
  unsigned short* WAbf = (unsigned short*)p;  p += (size_t)384 * HIDN * 2;
  float* afull = (float*)p;                   p += (size_t)TTOK * 384 * 4;
  float* aofull = (float*)p;                  p += (size_t)TTOK * 128 * 4;
  float* cosb = (float*)p;                    p += (size_t)SEQL * 64 * 4;
  float* sinb = (float*)p;                    p += (size_t)SEQL * 64 * 4;

  const int CVT_BLOCKS = (TTOK * HIDN) / 1024;
  const int CVT_WA = (128 * HIDN) / 1024;
  const int CONVW_BLOCKS = CVT_BLOCKS + (HIDN * 32) / 256;   // 16384 + 512
  dim3 g256(16, 16);

  hipFuncSetAttribute((const void*)gemm256_kernel<KEXT, 0>,
                      hipFuncAttributeMaxDynamicSharedMemorySize, 131072);
  hipFuncSetAttribute((const void*)gemm256_kernel<KEXT, 1>,
                      hipFuncAttributeMaxDynamicSharedMemorySize, 131072);
  hipFuncSetAttribute((const void*)gemm256_kernel<KEXT, 2>,
                      hipFuncAttributeMaxDynamicSharedMemorySize, 131072);

  rope_tab_kernel<<<(SEQL * 64) / 256, 256, 0, stream>>>(cosb, sinb);
  f2b_pad_kernel<<<CVT_BLOCKS, 256, 0, stream>>>(x, Xext);
  conv_wa3_kernel<<<3 * CVT_WA, 256, 0, stream>>>(wa_q, wa_k, wa_v, WAbf);
  gemm_bt_splitk_kernel<<<dim3(3, 32, 8), 256, 0, stream>>>(Xext, WAbf, tmp, 384, KEXT);
  reduce8_kernel<<<(TTOK * 384) / 1024, 256, 0, stream>>>(tmp, afull, TTOK * 384);

  // Q projection: lora-B folded; rope+bf16 fused into gemm epilogue
  conv_w_kernel<<<CONVW_BLOCKS, 256, 0, stream>>>(W[0], wb_q, Wext);
  afat_kernel<<<TTOK, 128, 0, stream>>>(afull, 0, 384, lidx, Xext);
  gemm256_kernel<KEXT, 1><<<g256, 512, 131072, stream>>>(Xext, Wext, qbuf, cosb, sinb);
  // K projection
  conv_w_kernel<<<CONVW_BLOCKS, 256, 0, stream>>>(W[1], wb_k, Wext);
  afat_kernel<<<TTOK, 128, 0, stream>>>(afull, 128, 384, lidx, Xext);
  gemm256_kernel<KEXT, 1><<<g256, 512, 131072, stream>>>(Xext, Wext, kbuf, cosb, sinb);
  // V projection (no rope: fused bf16 cast)
  conv_w_kernel<<<CONVW_BLOCKS, 256, 0, stream>>>(W[2], wb_v, Wext);
  afat_kernel<<<TTOK, 128, 0, stream>>>(afull, 256, 384, lidx, Xext);
  gemm256_kernel<KEXT, 2><<<g256, 512, 131072, stream>>>(Xext, Wext, vbuf, nullptr, nullptr);

  attn_kernel<<<dim3(8, 256), 256, 0, stream>>>(qbuf, kbuf, vbuf, Aext);

  // output projection: lora-A on attention output, then fused gemm -> out directly
  f2b_kernel<<<CVT_WA, 256, 0, stream>>>(wa_o, WAbf);
  gemm_bt_splitk_kernel<<<dim3(1, 32, 8), 256, 0, stream>>>(Aext, WAbf, tmp, 128, KEXT);
  reduce8_kernel<<<(TTOK * 128) / 1024, 256, 0, stream>>>(tmp, aofull, TTOK * 128);
  conv_w_kernel<<<CONVW_BLOCKS, 256, 0, stream>>>(W[3], wb_o, Wext);
  afat_kernel<<<TTOK, 128, 0, stream>>>(aofull, 0, 128, lidx, Aext);
  gemm256_kernel<KEXT, 0><<<g256, 512, 131072, stream>>>(Aext, Wext, out, nullptr, nullptr);
}